// Round 1
// baseline (90.165 us; speedup 1.0000x reference)
//
#include <hip/hip_runtime.h>

// RegionLayer (YOLOv2 region loss) on gfx950 — fused single-pass version, r1.
// B=16, A=5, nC=20, nH=nW=64, MAX_BOXES=50. Output: scalar loss (float32).
//
// r1 changes vs the 87.9us baseline:
//  - hot 50-box loop has a COMPILE-TIME trip count (invalid boxes padded inert
//    with scg=1e30) and #pragma unroll 10 -> LDS reads batch/pipeline instead
//    of one dependent lgkmcnt wait per iteration.
//  - ownership resolved at parse time into a 256-entry LDS map (atomicMax =
//    last-box-wins, matching the reference scan order); removes scode read +
//    compare + cndmask from the hot loop.
//  - b/a/p0 derived from blockIdx only (blocks never straddle an (b,a) plane)
//    so base addressing and anchor loads scalarize (s_load instead of VALU).
//
// conf_mask test is division-free: iou>0.6 <=> inter > 0.375*(area_p+area_g).
// Deterministic reduction: per-block partial -> d_ws, tiny reduce kernel
// overwrites d_out (no zero-init needed despite 0xAA poison).

#define NCLS 20
#define NA 5
#define NB 16
#define NH 64
#define NW 64
#define MAXB 50
#define OBJECT_SCALE 5.0f
#define BLOCKS_PER_B 80              // 5 anchors * (4096/256)
#define NBLOCKS (NB * BLOCKS_PER_B)  // 1280

__global__ __launch_bounds__(256) void region_loss_kernel(
    const float* __restrict__ output,
    const float* __restrict__ target,
    const float* __restrict__ anchors,
    float* __restrict__ part) {
    // ---- scalar (blockIdx-only) decomposition: a block covers 256 consecutive
    //      cells p0..p0+255 of one (b, a) plane ----
    const int b   = blockIdx.x / BLOCKS_PER_B;
    const int blk = blockIdx.x - b * BLOCKS_PER_B;
    const int a   = blk >> 4;            // 16 blocks per plane
    const int p0  = (blk & 15) << 8;
    const int p   = p0 + threadIdx.x;    // j*NW + i
    const int i = p & 63;
    const int j = p >> 6;

    __shared__ float4 scrn[MAXB];      // (x0, x1, y0, y1) box corners
    __shared__ float4 sctr[MAXB];      // (gx, gy, gw, gh) center form
    __shared__ float scg[MAXB];        // 0.375*gw*gh (1e30 for invalid: inert)
    __shared__ float scls[MAXB];
    __shared__ int   sown[256];        // box index owning this block's cell, or -1

    sown[threadIdx.x] = -1;
    __syncthreads();

    // ---- wave 0: parallel target parse for batch b ----
    if (threadIdx.x < 64) {
        const int t = threadIdx.x;
        float cls = 0.f, x = 0.f, y = 0.f, w = 0.f, h = 0.f;
        if (t < MAXB) {
            const float* tb = target + (b * MAXB + t) * 5;
            cls = tb[0]; x = tb[1]; y = tb[2]; w = tb[3]; h = tb[4];
        }
        // validity is a prefix: cumprod(x != 0) -> count trailing ones
        unsigned long long m = __ballot(x != 0.0f);
        const int nv = min(MAXB, (int)__ffsll(~m) - 1);
        if (t < MAXB) {
            float gx = x * NW, gy = y * NH, gw = w * NW, gh = h * NH;
            scrn[t] = make_float4(gx - 0.5f * gw, gx + 0.5f * gw,
                                  gy - 0.5f * gh, gy + 0.5f * gh);
            sctr[t] = make_float4(gx, gy, gw, gh);
            scg[t]  = (t < nv) ? 0.375f * gw * gh : 1e30f;
            scls[t] = cls;
            if (t < nv) {
                int gi = max(0, min(NW - 1, (int)gx));
                int gj = max(0, min(NH - 1, (int)gy));
                int best = 0; float bestv = -1.0f;
#pragma unroll
                for (int aa = 0; aa < NA; ++aa) {
                    float aw = anchors[2 * aa], ah = anchors[2 * aa + 1];
                    float inter = fminf(gw, aw) * fminf(gh, ah);
                    float uni = gw * gh + aw * ah - inter;
                    float r = inter / uni;
                    if (r > bestv) { bestv = r; best = aa; }
                }
                // cell code relative to this block; in-range iff best==a and
                // gj*64+gi in [p0, p0+256)  (the <<12 makes anchors disjoint)
                int rel = ((best << 12) | (gj << 6) | gi) - ((a << 12) | p0);
                if (rel >= 0 && rel < 256) atomicMax(&sown[rel], t);  // last wins
            }
        }
    }
    __syncthreads();

    // ---- per-cell prediction ----
    const float* base = output + ((size_t)(b * 125 + a * 25)) * 4096 + p;
    float xo = base[0];
    float yo = base[4096];
    float wo = base[2 * 4096];
    float ho = base[3 * 4096];
    float co = base[4 * 4096];

    float sigx = 1.0f / (1.0f + __expf(-xo));
    float sigy = 1.0f / (1.0f + __expf(-yo));
    float conf = 1.0f / (1.0f + __expf(-co));

    float aw = anchors[2 * a], ah = anchors[2 * a + 1];   // scalar loads (a uniform)
    float pw = __expf(wo) * aw;
    float ph = __expf(ho) * ah;
    float px = sigx + (float)i;
    float py = sigy + (float)j;
    float phw = 0.5f * pw, phh = 0.5f * ph;
    float pxl = px - phw, pxr = px + phw;
    float pyt = py - phh, pyb = py + phh;
    float area_p = pw * ph;
    float cp = 0.375f * area_p;        // THRESH/(1+THRESH) * area_p

    // any IoU(pred, gt) > 0.6  <=>  max_t (inter_t - 0.375*Ag_t) > 0.375*Ap
    float ovm = -1e30f;
#pragma unroll 10
    for (int t = 0; t < MAXB; ++t) {
        float4 g = scrn[t];            // LDS broadcast, conflict-free
        float cg = scg[t];
        float l  = fmaxf(pxl, g.x);
        float r  = fminf(pxr, g.y);
        float tt = fmaxf(pyt, g.z);
        float bb = fminf(pyb, g.w);
        float inter = fmaxf(r - l, 0.0f) * fmaxf(bb - tt, 0.0f);
        ovm = fmaxf(ovm, inter - cg);
    }
    const bool over = ovm > cp;
    const int own = sown[threadIdx.x];

    float conf_mask = over ? 0.0f : 1.0f;       // NOOBJECT_SCALE = 1
    float tconf = 0.0f;
    float loss = 0.0f;
    float tx = 0.5f, ty = 0.5f, tw = 0.0f, th = 0.0f;

    if (own >= 0) {
        float4 g = sctr[own];
        tx = g.x - (float)i;           // gi == i at the owner cell
        ty = g.y - (float)j;
        tw = __logf(g.z / aw);         // best_n == a at the owner cell
        th = __logf(g.w / ah);
        float4 c = scrn[own];
        float l = fmaxf(pxl, c.x);
        float r = fminf(pxr, c.y);
        float tt = fmaxf(pyt, c.z);
        float bb = fminf(pyb, c.w);
        float inter = fmaxf(r - l, 0.0f) * fmaxf(bb - tt, 0.0f);
        float uni = area_p + g.z * g.w - inter;
        tconf = inter / uni;
        conf_mask = OBJECT_SCALE;

        // class cross-entropy at this cell (CLASS_SCALE = 1)
        int tcls = (int)scls[own];
        float logits[NCLS];
        float mx = -1e30f;
#pragma unroll
        for (int c2 = 0; c2 < NCLS; ++c2) {
            logits[c2] = base[(5 + c2) * 4096];
            mx = fmaxf(mx, logits[c2]);
        }
        float s = 0.0f;
#pragma unroll
        for (int c2 = 0; c2 < NCLS; ++c2) s += __expf(logits[c2] - mx);
        loss += mx + __logf(s) - logits[tcls];
    }

    float dx = sigx - tx, dy = sigy - ty, dw = wo - tw, dh = ho - th;
    loss += 0.5f * (dx * dx + dy * dy + dw * dw + dh * dh);  // coord, cm==1
    float dc = conf - tconf;
    loss += 0.5f * conf_mask * dc * dc;                       // conf

    // ---- block reduction -> deterministic partial ----
#pragma unroll
    for (int off = 32; off > 0; off >>= 1) loss += __shfl_down(loss, off, 64);
    __shared__ float wsum[4];
    if ((threadIdx.x & 63) == 0) wsum[threadIdx.x >> 6] = loss;
    __syncthreads();
    if (threadIdx.x == 0) part[blockIdx.x] = wsum[0] + wsum[1] + wsum[2] + wsum[3];
}

__global__ __launch_bounds__(256) void reduce_kernel(const float* __restrict__ part,
                                                     float* __restrict__ out) {
    float s = 0.0f;
    for (int idx = threadIdx.x; idx < NBLOCKS; idx += 256) s += part[idx];
#pragma unroll
    for (int off = 32; off > 0; off >>= 1) s += __shfl_down(s, off, 64);
    __shared__ float wsum[4];
    if ((threadIdx.x & 63) == 0) wsum[threadIdx.x >> 6] = s;
    __syncthreads();
    if (threadIdx.x == 0) out[0] = wsum[0] + wsum[1] + wsum[2] + wsum[3];
}

extern "C" void kernel_launch(void* const* d_in, const int* in_sizes, int n_in,
                              void* d_out, int out_size, void* d_ws, size_t ws_size,
                              hipStream_t stream) {
    const float* output  = (const float*)d_in[0];
    const float* target  = (const float*)d_in[1];
    const float* anchors = (const float*)d_in[2];
    float* part = (float*)d_ws;   // NBLOCKS floats

    region_loss_kernel<<<NBLOCKS, 256, 0, stream>>>(output, target, anchors, part);
    reduce_kernel<<<1, 256, 0, stream>>>(part, (float*)d_out);
}